// Round 13
// baseline (452.824 us; speedup 1.0000x reference)
//
#include <hip/hip_runtime.h>
#include <hip/hip_bf16.h>

typedef __hip_bfloat16 bf16;
typedef __attribute__((ext_vector_type(8))) short bf16x8;
typedef __attribute__((ext_vector_type(4))) float f32x4;

// ---------- dtype-adaptive loads (flags are wave-uniform) ----------
__device__ __forceinline__ float ldf(const void* p, long long i, int f32){
  return f32 ? ((const float*)p)[i] : __bfloat162float(((const bf16*)p)[i]);
}
__device__ __forceinline__ int ldi(const void* p, long long i, int i64){
  return i64 ? (int)((const long long*)p)[i] : ((const int*)p)[i];
}
// exact bf16x4 -> f32x4 unpack (shift<<16)
__device__ __forceinline__ float4 bf4_to_f4(ushort4 v){
  float4 r;
  r.x = __uint_as_float((unsigned)v.x << 16);
  r.y = __uint_as_float((unsigned)v.y << 16);
  r.z = __uint_as_float((unsigned)v.z << 16);
  r.w = __uint_as_float((unsigned)v.w << 16);
  return r;
}

// ---------- sniff input dtypes once per launch + zero scratch ----------
__global__ void k_sniff(const void* __restrict__ x, const void* __restrict__ eidx,
                        int* __restrict__ flags, int* __restrict__ zp, int nzero){
  __shared__ int s_f, s_i;
  if (threadIdx.x == 0){ s_f = 0; s_i = 0; }
  __syncthreads();
  int t = threadIdx.x;
  const unsigned short* u = (const unsigned short*)x;
  int hits = 0;
  for (int k = t; k < 2048; k += 256){
    unsigned short v = u[2*k];
    int e = (v >> 7) & 0xFF;
    if (e == 0xFF || e == 0x00) hits++;
  }
  if (hits) atomicAdd(&s_f, 1);
  const int* ii = (const int*)eidx;
  int nz = 0;
  for (int k = t; k < 1024; k += 256){ if (ii[2*k+1] != 0) nz++; }
  if (nz) atomicAdd(&s_i, 1);
  for (int i = t; i < nzero; i += 256) zp[i] = 0;
  __syncthreads();
  if (threadIdx.x == 0){
    flags[0] = s_f ? 1 : 0;   // 1 = float32, 0 = bf16
    flags[1] = s_i ? 0 : 1;   // 1 = int64,   0 = int32
  }
}

// ================= binned CSR build (shift=8: 256-node buckets) =================

__global__ void __launch_bounds__(256) k_bhist(const void* __restrict__ eidx, long long E,
                       const int* __restrict__ flags, int shift, int NB,
                       int* __restrict__ bcnt){
  __shared__ int h[1024];
  int t = threadIdx.x;
  for (int b = t; b < NB; b += 256) h[b] = 0;
  __syncthreads();
  int i64 = flags[1];
  long long e0 = (long long)blockIdx.x*4096;
  long long e1 = e0 + 4096; if (e1 > E) e1 = E;
  for (long long e = e0 + t; e < e1; e += 256){
    int d = ldi(eidx, E + e, i64);
    atomicAdd(&h[d >> shift], 1);
  }
  __syncthreads();
  for (int b = t; b < NB; b += 256) if (h[b]) atomicAdd(&bcnt[b], h[b]);
}

__global__ void __launch_bounds__(256) k_bscan(const int* __restrict__ bcnt, int* __restrict__ bbase,
                       int NB, int E){
  __shared__ int tmp[256];
  int t = threadIdx.x;
  int v0 = (4*t+0 < NB) ? bcnt[4*t+0] : 0;
  int v1 = (4*t+1 < NB) ? bcnt[4*t+1] : 0;
  int v2 = (4*t+2 < NB) ? bcnt[4*t+2] : 0;
  int v3 = (4*t+3 < NB) ? bcnt[4*t+3] : 0;
  int s = v0+v1+v2+v3;
  tmp[t] = s;
  __syncthreads();
  for (int st = 1; st < 256; st <<= 1){
    int add = (t >= st) ? tmp[t-st] : 0;
    __syncthreads();
    tmp[t] += add;
    __syncthreads();
  }
  int run = tmp[t] - s;
  if (4*t+0 < NB){ bbase[4*t+0] = run; run += v0; }
  if (4*t+1 < NB){ bbase[4*t+1] = run; run += v1; }
  if (4*t+2 < NB){ bbase[4*t+2] = run; run += v2; }
  if (4*t+3 < NB){ bbase[4*t+3] = run; run += v3; }
  if (t == 255) bbase[NB] = E;
}

// 4096-edge chunks, 512 threads; wave-level shfl scan; dst cached in regs across passes
#define BINCH 4096
__global__ void __launch_bounds__(512) k_bin(const void* __restrict__ eidx, long long E,
                     const void* __restrict__ ew, const int* __restrict__ flags,
                     int shift, int NB, const int* __restrict__ bbase,
                     int* __restrict__ gcur, int2* __restrict__ csrTmp){
  __shared__ int bst[512];
  __shared__ int bcur[512];
  __shared__ int gof[512];
  __shared__ int wtot[8];
  __shared__ int2 ent[BINCH];
  __shared__ unsigned short entb[BINCH];
  int t = threadIdx.x;
  int lane = t & 63, wv = t >> 6;
  int i64 = flags[1], f32 = flags[0];
  long long e0 = (long long)blockIdx.x*BINCH;
  int cnt = (int)(((E - e0) < BINCH) ? (E - e0) : BINCH);
  int msk = (1 << shift) - 1;
  for (int b = t; b < NB; b += 512) bst[b] = 0;
  __syncthreads();
  int dcache[8];                       // BINCH/512 == 8 per-thread elements max
  int nit = 0;
  for (int i = t; i < cnt; i += 512){
    int d = ldi(eidx, E + e0 + i, i64);
    dcache[nit++] = d;
    atomicAdd(&bst[d >> shift], 1);
  }
  __syncthreads();
  int v = (t < NB) ? bst[t] : 0;
  // wave-level inclusive scan, then cross-wave combine (single barrier)
  int incl = v;
  #pragma unroll
  for (int st = 1; st < 64; st <<= 1){
    int u = __shfl_up(incl, st, 64);
    if (lane >= st) incl += u;
  }
  if (lane == 63) wtot[wv] = incl;
  __syncthreads();
  int wbase = 0;
  for (int i = 0; i < wv; ++i) wbase += wtot[i];
  int run = wbase + incl - v;       // exclusive prefix
  if (t < NB){
    bst[t] = run; bcur[t] = run;
    if (v) gof[t] = atomicAdd(&gcur[t], v);
  }
  __syncthreads();
  nit = 0;
  for (int i = t; i < cnt; i += 512){
    int d  = dcache[nit++];
    int sc = ldi(eidx, e0 + i, i64);
    float w = ldf(ew, e0 + i, f32);
    int b = d >> shift;
    int dl = d & msk;
    int pos = atomicAdd(&bcur[b], 1);
    ent[pos]  = make_int2((dl << 24) | sc, __float_as_int(w));
    entb[pos] = (unsigned short)b;
  }
  __syncthreads();
  for (int i = t; i < cnt; i += 512){
    int b = entb[i];
    int gpos = bbase[b] + gof[b] + (i - bst[b]);
    csrTmp[gpos] = ent[i];
  }
}

// per-bucket (1024 threads): counting sort by dst-low.
// Pass 1: ONE packed u64 LDS atomic per edge; csrTmp records cached in regs (<=12/thread).
// Scan: wave shfl + combine. csr.y = w*dinv[dst].
__global__ void __launch_bounds__(1024) k_bucket(const int2* __restrict__ csrTmp, const int* __restrict__ bbase,
                        int shift, int N, int E, int2* __restrict__ csr,
                        int* __restrict__ rowptr, float* __restrict__ dinv){
  __shared__ unsigned long long hw[256];
  __shared__ int   st4[4];
  __shared__ int   cur[256];
  __shared__ float sdv[256];
  int b = blockIdx.x, t = threadIdx.x;
  int base = bbase[b], cnt = bbase[b+1] - base;
  if (t < 256) hw[t] = 0ull;
  __syncthreads();
  int2 pc[12];                         // cache up to 12 per-thread records
  int nit = 0;
  for (int i = t; i < cnt; i += 1024){
    int2 p = csrTmp[base + i];
    if (nit < 12) pc[nit] = p;
    nit++;
    int dl = ((unsigned)p.x) >> 24;
    float w = __int_as_float(p.y);
    unsigned long long pk = ((unsigned long long)1 << 40)
                          + (unsigned long long)__float2uint_rn(w * 65536.0f);
    atomicAdd(&hw[dl], pk);
  }
  __syncthreads();
  int c = 0; float wsumv = 0.f;
  if (t < 256){
    unsigned long long vv = hw[t];
    c = (int)(vv >> 40);
    wsumv = (float)(vv & (((unsigned long long)1 << 40) - 1)) * (1.0f/65536.0f);
  }
  int lane = t & 63, wv = t >> 6;
  int incl = c;
  #pragma unroll
  for (int s2 = 1; s2 < 64; s2 <<= 1){
    int u = __shfl_up(incl, s2, 64);
    if (lane >= s2) incl += u;
  }
  if (t < 256 && lane == 63) st4[wv] = incl;
  __syncthreads();
  if (t < 256){
    int wbase = 0;
    for (int i = 0; i < wv; ++i) wbase += st4[i];
    int ex = wbase + incl - c;      // exclusive prefix
    cur[t] = ex;
    int n = (b << shift) + t;
    if (n < N){
      float deg = 1.f + wsumv;
      float di = (deg > 0.f) ? rsqrtf(fmaxf(deg, 1e-30f)) : 0.f;
      sdv[t] = di;
      dinv[n] = di;
      rowptr[n] = base + ex;
      if (n == N-1) rowptr[N] = E;
    }
  }
  __syncthreads();
  nit = 0;
  for (int i = t; i < cnt; i += 1024){
    int2 p = (nit < 12) ? pc[nit] : csrTmp[base + i];
    nit++;
    int dl = ((unsigned)p.x) >> 24;
    int pos = atomicAdd(&cur[dl], 1);
    float nm = __int_as_float(p.y) * sdv[dl];       // w * dinv[dst]
    csr[base + pos] = make_int2(p.x & 0xFFFFFF, __float_as_int(nm));
  }
}

// ---------- plain pull: wave/node, round-robin grid-stride, 4-deep ILP, bf16 zp ----------
// zp = bf16(dinv*(hW)); agg[n] = dinv[n]*zp[n] + sum csr.y*zp[src]   (f32 out for pool)
__global__ void __launch_bounds__(256) k_pull(const int2* __restrict__ csr, const int* __restrict__ rowptr,
                       const float* __restrict__ dinv, const void* __restrict__ zp,
                       float* __restrict__ agg, int N){
  int lane = threadIdx.x & 63;
  int g = lane >> 3;            // edge subgroup 0..7
  int q = lane & 7;             // feature quad 0..7
  const ushort4* h4 = (const ushort4*)zp;   // 8 x ushort4 per 64B row
  int nwaves = gridDim.x*4;
  for (int n = blockIdx.x*4 + (threadIdx.x >> 6); n < N; n += nwaves){
    int s0 = rowptr[n], s1 = rowptr[n+1];
    float4 acc = make_float4(0.f,0.f,0.f,0.f);
    if (g == 0){
      float di = dinv[n];
      float4 hv = bf4_to_f4(h4[n*8 + q]);
      acc.x = di*hv.x; acc.y = di*hv.y; acc.z = di*hv.z; acc.w = di*hv.w;
    }
    int j = s0 + g;
    for (; j + 24 < s1; j += 32){
      int2 p0 = csr[j];
      int2 p1 = csr[j+8];
      int2 p2 = csr[j+16];
      int2 p3 = csr[j+24];
      float4 h0 = bf4_to_f4(h4[(p0.x<<3)+q]);
      float4 h1 = bf4_to_f4(h4[(p1.x<<3)+q]);
      float4 h2 = bf4_to_f4(h4[(p2.x<<3)+q]);
      float4 h3 = bf4_to_f4(h4[(p3.x<<3)+q]);
      float n0 = __int_as_float(p0.y), n1 = __int_as_float(p1.y);
      float n2 = __int_as_float(p2.y), n3 = __int_as_float(p3.y);
      acc.x = fmaf(n0, h0.x, acc.x); acc.y = fmaf(n0, h0.y, acc.y);
      acc.z = fmaf(n0, h0.z, acc.z); acc.w = fmaf(n0, h0.w, acc.w);
      acc.x = fmaf(n1, h1.x, acc.x); acc.y = fmaf(n1, h1.y, acc.y);
      acc.z = fmaf(n1, h1.z, acc.z); acc.w = fmaf(n1, h1.w, acc.w);
      acc.x = fmaf(n2, h2.x, acc.x); acc.y = fmaf(n2, h2.y, acc.y);
      acc.z = fmaf(n2, h2.z, acc.z); acc.w = fmaf(n2, h2.w, acc.w);
      acc.x = fmaf(n3, h3.x, acc.x); acc.y = fmaf(n3, h3.y, acc.y);
      acc.z = fmaf(n3, h3.z, acc.z); acc.w = fmaf(n3, h3.w, acc.w);
    }
    if (j + 8 < s1){
      int2 p0 = csr[j];
      int2 p1 = csr[j+8];
      float4 h0 = bf4_to_f4(h4[(p0.x<<3)+q]);
      float4 h1 = bf4_to_f4(h4[(p1.x<<3)+q]);
      float n0 = __int_as_float(p0.y), n1 = __int_as_float(p1.y);
      acc.x = fmaf(n0, h0.x, acc.x); acc.y = fmaf(n0, h0.y, acc.y);
      acc.z = fmaf(n0, h0.z, acc.z); acc.w = fmaf(n0, h0.w, acc.w);
      acc.x = fmaf(n1, h1.x, acc.x); acc.y = fmaf(n1, h1.y, acc.y);
      acc.z = fmaf(n1, h1.z, acc.z); acc.w = fmaf(n1, h1.w, acc.w);
      j += 16;
    }
    if (j < s1){
      int2 p = csr[j];
      float nm = __int_as_float(p.y);
      float4 hv = bf4_to_f4(h4[(p.x<<3)+q]);
      acc.x = fmaf(nm, hv.x, acc.x); acc.y = fmaf(nm, hv.y, acc.y);
      acc.z = fmaf(nm, hv.z, acc.z); acc.w = fmaf(nm, hv.w, acc.w);
    }
    #pragma unroll
    for (int st = 8; st < 64; st <<= 1){
      acc.x += __shfl_xor(acc.x, st, 64);
      acc.y += __shfl_xor(acc.y, st, 64);
      acc.z += __shfl_xor(acc.z, st, 64);
      acc.w += __shfl_xor(acc.w, st, 64);
    }
    if (g == 0) ((float4*)agg)[n*8 + q] = acc;
  }
}

// ---------- fused pull + next-layer transform (round-robin grid-stride, wave-private LDS epilogue) ----------
// out[n] = bf16( dinv[n] * ( relu(agg[n] + b_prev) @ W_next ) )   [32x32 GEMV per node]
__global__ void __launch_bounds__(256) k_pullT(const int2* __restrict__ csr, const int* __restrict__ rowptr,
                        const float* __restrict__ dinv, const void* __restrict__ zp,
                        const void* __restrict__ Wn, const void* __restrict__ bn,
                        const int* __restrict__ flags,
                        void* __restrict__ out, int N){
  __shared__ float  ws[32*32];   // W_next [k][f]
  __shared__ float4 bs4[8];      // bias (32 f)
  __shared__ float4 sT4[4][8];   // per-wave t = relu(agg+b), wave-private slot
  int tid = threadIdx.x;
  int f32 = flags[0];
  for (int i = tid; i < 1024; i += 256) ws[i] = ldf(Wn, i, f32);
  if (tid < 32) ((float*)bs4)[tid] = ldf(bn, tid, f32);
  __syncthreads();              // only barrier: uniform-cost weight preload

  int lane = tid & 63;
  int wave = tid >> 6;
  int g = lane >> 3;            // edge subgroup 0..7
  int q = lane & 7;             // feature quad 0..7
  int f  = lane & 31;
  int hh = lane >> 5;
  const ushort4* h4 = (const ushort4*)zp;
  const float4* tr4 = &sT4[wave][hh*4];
  int nwaves = gridDim.x*4;
  for (int n = blockIdx.x*4 + wave; n < N; n += nwaves){
    int s0 = rowptr[n], s1 = rowptr[n+1];
    float din = dinv[n];
    float4 acc = make_float4(0.f,0.f,0.f,0.f);
    if (g == 0){
      float4 hv = bf4_to_f4(h4[n*8 + q]);
      acc.x = din*hv.x; acc.y = din*hv.y; acc.z = din*hv.z; acc.w = din*hv.w;
    }
    int j = s0 + g;
    for (; j + 24 < s1; j += 32){
      int2 p0 = csr[j];
      int2 p1 = csr[j+8];
      int2 p2 = csr[j+16];
      int2 p3 = csr[j+24];
      float4 h0 = bf4_to_f4(h4[(p0.x<<3)+q]);
      float4 h1 = bf4_to_f4(h4[(p1.x<<3)+q]);
      float4 h2 = bf4_to_f4(h4[(p2.x<<3)+q]);
      float4 h3 = bf4_to_f4(h4[(p3.x<<3)+q]);
      float n0 = __int_as_float(p0.y), n1 = __int_as_float(p1.y);
      float n2 = __int_as_float(p2.y), n3 = __int_as_float(p3.y);
      acc.x = fmaf(n0, h0.x, acc.x); acc.y = fmaf(n0, h0.y, acc.y);
      acc.z = fmaf(n0, h0.z, acc.z); acc.w = fmaf(n0, h0.w, acc.w);
      acc.x = fmaf(n1, h1.x, acc.x); acc.y = fmaf(n1, h1.y, acc.y);
      acc.z = fmaf(n1, h1.z, acc.z); acc.w = fmaf(n1, h1.w, acc.w);
      acc.x = fmaf(n2, h2.x, acc.x); acc.y = fmaf(n2, h2.y, acc.y);
      acc.z = fmaf(n2, h2.z, acc.z); acc.w = fmaf(n2, h2.w, acc.w);
      acc.x = fmaf(n3, h3.x, acc.x); acc.y = fmaf(n3, h3.y, acc.y);
      acc.z = fmaf(n3, h3.z, acc.z); acc.w = fmaf(n3, h3.w, acc.w);
    }
    if (j + 8 < s1){
      int2 p0 = csr[j];
      int2 p1 = csr[j+8];
      float4 h0 = bf4_to_f4(h4[(p0.x<<3)+q]);
      float4 h1 = bf4_to_f4(h4[(p1.x<<3)+q]);
      float n0 = __int_as_float(p0.y), n1 = __int_as_float(p1.y);
      acc.x = fmaf(n0, h0.x, acc.x); acc.y = fmaf(n0, h0.y, acc.y);
      acc.z = fmaf(n0, h0.z, acc.z); acc.w = fmaf(n0, h0.w, acc.w);
      acc.x = fmaf(n1, h1.x, acc.x); acc.y = fmaf(n1, h1.y, acc.y);
      acc.z = fmaf(n1, h1.z, acc.z); acc.w = fmaf(n1, h1.w, acc.w);
      j += 16;
    }
    if (j < s1){
      int2 p = csr[j];
      float nm = __int_as_float(p.y);
      float4 hv = bf4_to_f4(h4[(p.x<<3)+q]);
      acc.x = fmaf(nm, hv.x, acc.x); acc.y = fmaf(nm, hv.y, acc.y);
      acc.z = fmaf(nm, hv.z, acc.z); acc.w = fmaf(nm, hv.w, acc.w);
    }
    #pragma unroll
    for (int st = 8; st < 64; st <<= 1){
      acc.x += __shfl_xor(acc.x, st, 64);
      acc.y += __shfl_xor(acc.y, st, 64);
      acc.z += __shfl_xor(acc.z, st, 64);
      acc.w += __shfl_xor(acc.w, st, 64);
    }
    // t = relu(agg + b_prev) staged to this wave's private LDS row (no barrier needed)
    if (g == 0){
      float4 b4 = bs4[q];
      float4 t;
      t.x = fmaxf(acc.x + b4.x, 0.f);
      t.y = fmaxf(acc.y + b4.y, 0.f);
      t.z = fmaxf(acc.z + b4.z, 0.f);
      t.w = fmaxf(acc.w + b4.w, 0.f);
      sT4[wave][q] = t;
    }
    // 32x32 GEMV: lane (f, hh) does k in [16*hh, 16*hh+16).
    float s = 0.f;
    #pragma unroll
    for (int i = 0; i < 4; ++i){
      float4 tv = tr4[i];
      int k = hh*16 + i*4;
      s = fmaf(tv.x, ws[(k+0)*32 + f], s);
      s = fmaf(tv.y, ws[(k+1)*32 + f], s);
      s = fmaf(tv.z, ws[(k+2)*32 + f], s);
      s = fmaf(tv.w, ws[(k+3)*32 + f], s);
    }
    s += __shfl_xor(s, 32, 64);
    if (hh == 0) ((bf16*)out)[n*32 + f] = __float2bfloat16(din * s);
  }
}

// ---------- layer-1 matmul ----------
__global__ void __launch_bounds__(256) k_mm1(const void* __restrict__ x, const void* __restrict__ W,
                      const int* __restrict__ flags, const float* __restrict__ dinv,
                      int mul_dinv, void* __restrict__ out, int N, int out_bf16){
  __shared__ float Ws[128*32];
  __shared__ float xs[32*128];
  int f32 = flags[0];
  float* out_f = (float*)out;
  bf16*  out_h = (bf16*)out;
  if (!f32){
    int wave = threadIdx.x >> 6;
    int lane = threadIdx.x & 63;
    int m = lane & 15, quad = lane >> 4;
    long long tile = (long long)blockIdx.x*4 + wave;
    int row0 = (int)(tile*16);
    if (row0 >= N) return;
    const short* xp = (const short*)x;
    const short* wp = (const short*)W;
    int row = row0 + m;
    bool rv = row < N;
    bf16x8 a[4];
    #pragma unroll
    for (int kc = 0; kc < 4; ++kc){
      if (rv) a[kc] = *(const bf16x8*)(xp + (long long)row*128 + kc*32 + quad*8);
      else    a[kc] = (bf16x8)(short)0;
    }
    #pragma unroll
    for (int nt = 0; nt < 2; ++nt){
      f32x4 acc = {0.f,0.f,0.f,0.f};
      #pragma unroll
      for (int kc = 0; kc < 4; ++kc){
        bf16x8 bfr;
        #pragma unroll
        for (int j = 0; j < 8; ++j)
          bfr[j] = wp[(kc*32 + quad*8 + j)*32 + nt*16 + m];
        acc = __builtin_amdgcn_mfma_f32_16x16x32_bf16(a[kc], bfr, acc, 0, 0, 0);
      }
      #pragma unroll
      for (int r = 0; r < 4; ++r){
        int rr = row0 + quad*4 + r;
        if (rr < N){
          float v = acc[r];
          if (mul_dinv) v *= dinv[rr];
          long long idx = (long long)rr*32 + nt*16 + m;
          if (out_bf16) out_h[idx] = __float2bfloat16(v);
          else          out_f[idx] = v;
        }
      }
    }
    return;
  }
  // ---- f32 fallback (legacy) ----
  int tid = threadIdx.x;
  for (int i = tid; i < 4096; i += 256) Ws[i] = ((const float*)W)[i];
  int n0 = blockIdx.x*32;
  for (int i = tid; i < 4096; i += 256){
    int r = i >> 7, k = i & 127, n = n0 + r;
    xs[i] = (n < N) ? ((const float*)x)[(long long)n*128 + k] : 0.f;
  }
  __syncthreads();
  int f = tid & 31, r = tid >> 5;
  float a0=0.f, a1=0.f, a2=0.f, a3=0.f;
  for (int k = 0; k < 128; ++k){
    float w = Ws[k*32+f];
    a0 = fmaf(xs[(r    )*128+k], w, a0);
    a1 = fmaf(xs[(r+ 8)*128+k], w, a1);
    a2 = fmaf(xs[(r+16)*128+k], w, a2);
    a3 = fmaf(xs[(r+24)*128+k], w, a3);
  }
  #pragma unroll 4
  for (int rr = 0; rr < 4; ++rr){
    int n = n0 + r + rr*8;
    float v = (rr==0)?a0:(rr==1)?a1:(rr==2)?a2:a3;
    if (n < N){
      if (mul_dinv) v *= dinv[n];
      if (out_bf16) out_h[n*32+f] = __float2bfloat16(v);
      else          out_f[n*32+f] = v;
    }
  }
}

// ---------- hidden matmul (fallback path only) ----------
__global__ void k_mmh(const float* __restrict__ in, const void* __restrict__ bias, int do_relu,
                      const void* __restrict__ W, const int* __restrict__ flags,
                      const float* __restrict__ dinv, int mul_dinv,
                      float* __restrict__ out, int N){
  __shared__ float Wt[32*36];
  __shared__ float xs[32*32];
  int tid = threadIdx.x;
  int f32 = flags[0];
  for (int i = tid; i < 1024; i += 256){
    int k = i >> 5, f = i & 31;
    Wt[f*36 + k] = ldf(W, i, f32);
  }
  int n0 = blockIdx.x*32;
  for (int i = tid; i < 1024; i += 256){
    int r = i >> 5, k = i & 31, n = n0 + r;
    float v = 0.f;
    if (n < N){
      v = in[(long long)n*32+k] + ldf(bias, k, f32);
      if (do_relu) v = fmaxf(v, 0.f);
    }
    xs[i] = v;
  }
  __syncthreads();
  int f = tid & 31, r = tid >> 5;
  const float4* xs4 = (const float4*)xs;
  float a0=0.f, a1=0.f, a2=0.f, a3=0.f;
  #pragma unroll
  for (int kc = 0; kc < 8; ++kc){
    float4 wv = *(const float4*)&Wt[f*36 + kc*4];
    float4 x0 = xs4[(r    )*8 + kc];
    float4 x1 = xs4[(r+ 8)*8 + kc];
    float4 x2 = xs4[(r+16)*8 + kc];
    float4 x3 = xs4[(r+24)*8 + kc];
    a0 = fmaf(x0.x,wv.x,fmaf(x0.y,wv.y,fmaf(x0.z,wv.z,fmaf(x0.w,wv.w,a0))));
    a1 = fmaf(x1.x,wv.x,fmaf(x1.y,wv.y,fmaf(x1.z,wv.z,fmaf(x1.w,wv.w,a1))));
    a2 = fmaf(x2.x,wv.x,fmaf(x2.y,wv.y,fmaf(x2.z,wv.z,fmaf(x2.w,wv.w,a2))));
    a3 = fmaf(x3.x,wv.x,fmaf(x3.y,wv.y,fmaf(x3.z,wv.z,fmaf(x3.w,wv.w,a3))));
  }
  int n;
  n = n0+r;    if (n < N) out[n*32+f] = mul_dinv ? a0*dinv[n] : a0;
  n = n0+r+8;  if (n < N) out[n*32+f] = mul_dinv ? a1*dinv[n] : a1;
  n = n0+r+16; if (n < N) out[n*32+f] = mul_dinv ? a2*dinv[n] : a2;
  n = n0+r+24; if (n < N) out[n*32+f] = mul_dinv ? a3*dinv[n] : a3;
}

// ---------- two-phase mean pool ----------
__device__ __forceinline__ int lower_bound_i(const void* __restrict__ a, int n, int v, int i64){
  int lo = 0, hi = n;
  while (lo < hi){ int mid = (lo+hi) >> 1; if (ldi(a, mid, i64) < v) lo = mid+1; else hi = mid; }
  return lo;
}

// phase 1: 128 rows/block; running accumulator per thread, flush on graph change
__global__ void k_pool1(const float* __restrict__ agg, const void* __restrict__ batch,
                        const int* __restrict__ flags, float* __restrict__ gacc, int N){
  int i64 = flags[1];
  int f = threadIdx.x & 31, r = threadIdx.x >> 5;
  long long start = (long long)blockIdx.x*128;
  long long end = start + 128; if (end > N) end = N;
  float acc = 0.f; int curg = -1;
  for (long long n = start + r; n < end; n += 8){
    int g = ldi(batch, n, i64);
    if (g != curg){
      if (curg >= 0) atomicAdd(&gacc[curg*32 + f], acc);
      acc = 0.f; curg = g;
    }
    acc += agg[n*32 + f];
  }
  if (curg >= 0) atomicAdd(&gacc[curg*32 + f], acc);
}

// legacy single-phase pool (fallback path)
__global__ void k_pool(const float* __restrict__ agg, const void* __restrict__ b3,
                       const void* __restrict__ batch, const int* __restrict__ flags,
                       float* __restrict__ gpool, int N){
  int f32 = flags[0], i64 = flags[1];
  int g = blockIdx.x;
  int start = lower_bound_i(batch, N, g, i64);
  int end   = lower_bound_i(batch, N, g+1, i64);
  int tid = threadIdx.x;
  int f = tid & 31, r = tid >> 5;
  float acc = 0.f;
  for (int n = start + r; n < end; n += 8) acc += agg[n*32+f];
  __shared__ float red[8][32];
  red[r][f] = acc;
  __syncthreads();
  if (r == 0){
    float s = red[0][f];
    #pragma unroll
    for (int j = 1; j < 8; ++j) s += red[j][f];
    int c = end - start;
    float gv = (c > 0) ? (s / (float)c + ldf(b3, f, f32)) : 0.f;
    gpool[g*32+f] = gv;
  }
}

// ---------- multi-block MLP head: (G+3)/4 blocks, 4 graphs/block ----------
__global__ void __launch_bounds__(256) k_mlpG(const float* __restrict__ gacc,
                      const void* __restrict__ batch, const void* __restrict__ b3,
                      const void* __restrict__ L1w, const void* __restrict__ L1b,
                      const void* __restrict__ L2w, const void* __restrict__ L2b,
                      const void* __restrict__ L3w, const void* __restrict__ L3b,
                      const void* __restrict__ L4w, const void* __restrict__ L4b,
                      const int* __restrict__ flags, void* __restrict__ out, int N, int G){
  __shared__ float ws1[32*64];
  __shared__ float ws2[64*64];
  __shared__ float ws3[64*64];
  __shared__ float ws4[64*10];
  __shared__ float wb1[64], wb2[64], wb3[64], wb4[10], b3s[32];
  __shared__ float gin[4*32];
  __shared__ float A[4*64];
  __shared__ float B[4*64];
  __shared__ int   sb[5];
  int tid = threadIdx.x;
  int f32 = flags[0], i64 = flags[1];
  int g0 = blockIdx.x*4;

  // one parallel burst: all weights + biases + graph bounds
  for (int i = tid; i < 2048; i += 256) ws1[i] = ldf(L1w, i, f32);
  for (int i = tid; i < 4096; i += 256) ws2[i] = ldf(L2w, i, f32);
  for (int i = tid; i < 4096; i += 256) ws3[i] = ldf(L3w, i, f32);
  for (int i = tid; i < 640;  i += 256) ws4[i] = ldf(L4w, i, f32);
  if (tid < 64) wb1[tid] = ldf(L1b, tid, f32);
  else if (tid >= 64 && tid < 128) wb2[tid-64] = ldf(L2b, tid-64, f32);
  else if (tid >= 128 && tid < 192) wb3[tid-128] = ldf(L3b, tid-128, f32);
  else if (tid >= 192 && tid < 202) wb4[tid-192] = ldf(L4b, tid-192, f32);
  else if (tid >= 224) b3s[tid-224] = ldf(b3, tid-224, f32);
  if (tid >= 202 && tid < 207){
    int gg = g0 + (tid - 202);
    sb[tid-202] = (gg <= G) ? lower_bound_i(batch, N, gg, i64) : N;
  }
  __syncthreads();
  // pool phase 2 for this block's 4 graphs
  for (int i = tid; i < 128; i += 256){
    int g = i >> 5, f = i & 31;
    int gg = g0 + g;
    float v = 0.f;
    if (gg < G){
      int c = sb[g+1] - sb[g];
      v = (c > 0) ? gacc[gg*32 + f]/(float)c + b3s[f] : 0.f;
    }
    gin[i] = v;
  }
  __syncthreads();
  // L1: 32 -> 64, relu
  {
    int g = tid >> 6, j = tid & 63;
    float a = wb1[j];
    #pragma unroll
    for (int k = 0; k < 32; ++k) a = fmaf(gin[g*32+k], ws1[k*64+j], a);
    A[g*64+j] = fmaxf(a, 0.f);
  }
  __syncthreads();
  // L2: 64 -> 64, relu
  {
    int g = tid >> 6, j = tid & 63;
    float a = wb2[j];
    #pragma unroll
    for (int k = 0; k < 64; ++k) a = fmaf(A[g*64+k], ws2[k*64+j], a);
    B[g*64+j] = fmaxf(a, 0.f);
  }
  __syncthreads();
  // L3: 64 -> 64, relu
  {
    int g = tid >> 6, j = tid & 63;
    float a = wb3[j];
    #pragma unroll
    for (int k = 0; k < 64; ++k) a = fmaf(B[g*64+k], ws3[k*64+j], a);
    A[g*64+j] = fmaxf(a, 0.f);
  }
  __syncthreads();
  // L4: 64 -> 10
  if (tid < 40){
    int g = tid / 10, c = tid % 10;
    int gg = g0 + g;
    if (gg < G){
      float a = wb4[c];
      #pragma unroll
      for (int k = 0; k < 64; ++k) a = fmaf(A[g*64+k], ws4[k*10+c], a);
      if (f32) ((float*)out)[gg*10+c] = a;
      else     ((bf16*)out)[gg*10+c]  = __float2bfloat16(a);
    }
  }
}

// ---------- legacy MLP head (fallback path) ----------
__global__ void __launch_bounds__(256, 1) k_mlp(const float* __restrict__ gpool,
                      const void* __restrict__ L1w, const void* __restrict__ L1b,
                      const void* __restrict__ L2w, const void* __restrict__ L2b,
                      const void* __restrict__ L3w, const void* __restrict__ L3b,
                      const void* __restrict__ L4w, const void* __restrict__ L4b,
                      const int* __restrict__ flags, void* __restrict__ out){
  __shared__ float gin[64*32];
  __shared__ float A[64*65];
  __shared__ float B[64*65];
  __shared__ float ws[64*64];
  __shared__ float wb[64];
  int tid = threadIdx.x;
  int f32 = flags[0];
  int j  = tid & 63;
  int i0 = tid >> 6;
  float acc[16];

  for (int i = tid; i < 64*32; i += 256) gin[i] = gpool[i];
  for (int i = tid; i < 2048; i += 256) ws[i] = ldf(L1w, i, f32);
  if (tid < 64) wb[tid] = ldf(L1b, tid, f32);
  __syncthreads();
  #pragma unroll
  for (int r = 0; r < 16; ++r) acc[r] = wb[j];
  for (int k = 0; k < 32; ++k){
    float w = ws[k*64+j];
    #pragma unroll
    for (int r = 0; r < 16; ++r) acc[r] = fmaf(gin[(i0+4*r)*32+k], w, acc[r]);
  }
  #pragma unroll
  for (int r = 0; r < 16; ++r) A[(i0+4*r)*65+j] = fmaxf(acc[r], 0.f);
  __syncthreads();
  for (int i = tid; i < 4096; i += 256) ws[i] = ldf(L2w, i, f32);
  if (tid < 64) wb[tid] = ldf(L2b, tid, f32);
  __syncthreads();
  #pragma unroll
  for (int r = 0; r < 16; ++r) acc[r] = wb[j];
  for (int k = 0; k < 64; ++k){
    float w = ws[k*64+j];
    #pragma unroll
    for (int r = 0; r < 16; ++r) acc[r] = fmaf(A[(i0+4*r)*65+k], w, acc[r]);
  }
  #pragma unroll
  for (int r = 0; r < 16; ++r) B[(i0+4*r)*65+j] = fmaxf(acc[r], 0.f);
  __syncthreads();
  for (int i = tid; i < 4096; i += 256) ws[i] = ldf(L3w, i, f32);
  if (tid < 64) wb[tid] = ldf(L3b, tid, f32);
  __syncthreads();
  #pragma unroll
  for (int r = 0; r < 16; ++r) acc[r] = wb[j];
  for (int k = 0; k < 64; ++k){
    float w = ws[k*64+j];
    #pragma unroll
    for (int r = 0; r < 16; ++r) acc[r] = fmaf(B[(i0+4*r)*65+k], w, acc[r]);
  }
  #pragma unroll
  for (int r = 0; r < 16; ++r) A[(i0+4*r)*65+j] = fmaxf(acc[r], 0.f);
  __syncthreads();
  for (int i = tid; i < 640; i += 256) ws[i] = ldf(L4w, i, f32);
  if (tid < 10) wb[tid] = ldf(L4b, tid, f32);
  __syncthreads();
  if (tid < 64){
    int row = tid;
    float a10[10];
    #pragma unroll
    for (int c = 0; c < 10; ++c) a10[c] = wb[c];
    for (int k = 0; k < 64; ++k){
      float av = A[row*65+k];
      #pragma unroll
      for (int c = 0; c < 10; ++c) a10[c] = fmaf(av, ws[k*10+c], a10[c]);
    }
    #pragma unroll
    for (int c = 0; c < 10; ++c){
      if (f32) ((float*)out)[row*10+c] = a10[c];
      else     ((bf16*)out)[row*10+c]  = __float2bfloat16(a10[c]);
    }
  }
}

// ---------- fallback (atomic-scatter path, small ws) ----------
__global__ void k_init_deg(float* __restrict__ deg, int N){
  int i = blockIdx.x*256 + threadIdx.x;
  if (i < N) deg[i] = 1.0f;
}
__global__ void k_deg_accum(const void* __restrict__ eidx, long long E,
                            const void* __restrict__ w, const int* __restrict__ flags,
                            float* __restrict__ deg){
  long long e = (long long)blockIdx.x*256 + threadIdx.x;
  if (e < E){
    int f32 = flags[0], i64 = flags[1];
    atomicAdd(&deg[ldi(eidx, E + e, i64)], ldf(w, e, f32));
  }
}
__global__ void k_dinv(float* __restrict__ deg, int N){
  int i = blockIdx.x*256 + threadIdx.x;
  if (i < N){
    float d = deg[i];
    deg[i] = (d > 0.f) ? rsqrtf(fmaxf(d, 1e-30f)) : 0.f;
  }
}
__global__ void k_norm(const void* __restrict__ eidx, long long E,
                       const void* __restrict__ w, const float* __restrict__ dinv,
                       const int* __restrict__ flags, float* __restrict__ nrm){
  long long e = (long long)blockIdx.x*256 + threadIdx.x;
  if (e < E){
    int f32 = flags[0], i64 = flags[1];
    int s = ldi(eidx, e, i64), d = ldi(eidx, E + e, i64);
    nrm[e] = dinv[s] * ldf(w, e, f32) * dinv[d];
  }
}
__global__ void k_selfloop(const float* __restrict__ hlin, const float* __restrict__ dinv,
                           float* __restrict__ agg, int N){
  int idx = blockIdx.x*256 + threadIdx.x;
  if (idx < N*32){
    int n = idx >> 5;
    float di = dinv[n];
    agg[idx] = di*di*hlin[idx];
  }
}
__global__ void k_scatter(const void* __restrict__ eidx, long long E,
                          const float* __restrict__ nrm, const int* __restrict__ flags,
                          const float* __restrict__ hlin, float* __restrict__ agg){
  long long idx = (long long)blockIdx.x*256 + threadIdx.x;
  if (idx < E*32){
    int i64 = flags[1];
    long long e = idx >> 5;
    int f = (int)(idx & 31);
    int s = ldi(eidx, e, i64), d = ldi(eidx, E + e, i64);
    atomicAdd(&agg[(long long)d*32 + f], nrm[e] * hlin[(long long)s*32 + f]);
  }
}

extern "C" void kernel_launch(void* const* d_in, const int* in_sizes, int n_in,
                              void* d_out, int out_size, void* d_ws, size_t ws_size,
                              hipStream_t stream){
  const void* x   = d_in[0];
  const void* ew  = d_in[1];
  const void* W1  = d_in[2];
  const void* b1  = d_in[3];
  const void* W2  = d_in[4];
  const void* b2  = d_in[5];
  const void* W3  = d_in[6];
  const void* b3  = d_in[7];
  const void* L1w = d_in[8];  const void* L1b = d_in[9];
  const void* L2w = d_in[10]; const void* L2b = d_in[11];
  const void* L3w = d_in[12]; const void* L3b = d_in[13];
  const void* L4w = d_in[14]; const void* L4b = d_in[15];
  const void* eidx  = d_in[16];
  const void* batch = d_in[17];
  const long long E = in_sizes[1];
  const int N = in_sizes[17];
  const int G = out_size / 10;

  dim3 b(256);
  int gN   = (N + 255)/256;
  int gE   = (int)((E + 255)/256);
  int gMM  = (N + 31)/32;
  int gMM1 = (N + 63)/64;
  int gNd4 = (N + 3)/4;
  int gPull = gNd4 < 2048 ? gNd4 : 2048;   // round-robin grid-stride: ~8 blocks/CU
  int gBH  = (int)((E + 4095)/4096);
  int gBN  = (int)((E + BINCH - 1)/BINCH);
  int gP1  = (N + 127)/128;

  const int shift = 8;                       // 256-node buckets
  int NB = (N + 255) >> 8;

  auto AL = [](size_t v){ return (v + 255) & ~(size_t)255; };

  char* base = (char*)d_ws;
  size_t off = 0;
  size_t o_flags = off; off += AL(64*4);
  size_t o_rowp  = off; off += AL((size_t)(N+1)*4);
  size_t o_dinv  = off; off += AL((size_t)N*4);
  size_t o_bbase = off; off += AL((size_t)(NB+1)*4);
  size_t o_bcnt  = off; off += AL((size_t)NB*4) + AL((size_t)NB*4) + AL((size_t)G*32*4);  // bcnt+gcur+gacc
  size_t o_csr   = off; off += AL((size_t)E*8);
  size_t o_tmp   = off; off += AL((size_t)E*8);
  size_t o_bufA  = off; off += AL((size_t)N*128);
  size_t o_bufB  = off; off += AL((size_t)N*128);
  size_t o_gp    = off; off += AL((size_t)G*32*4);
  size_t needed  = off;

  if (ws_size >= needed && NB <= 512 && N < (1<<24) && G <= 64){
    int*   flags  = (int*)(base + o_flags);
    int*   rowptr = (int*)(base + o_rowp);
    float* dinv   = (float*)(base + o_dinv);
    int*   bbase  = (int*)(base + o_bbase);
    int*   bcnt   = (int*)(base + o_bcnt);
    int*   gcur   = (int*)(base + o_bcnt + AL((size_t)NB*4));
    float* gacc   = (float*)(base + o_bcnt + AL((size_t)NB*4) + AL((size_t)NB*4));
    int2*  csr    = (int2*)(base + o_csr);
    int2*  csrTmp = (int2*)(base + o_tmp);
    float* bufA   = (float*)(base + o_bufA);
    float* bufB   = (float*)(base + o_bufB);

    int nzero = (int)((AL((size_t)NB*4) + AL((size_t)NB*4))/4) + G*32;  // bcnt+gcur+gacc contiguous
    k_sniff <<<1,    b, 0, stream>>>(x, eidx, flags, bcnt, nzero);
    k_bhist <<<gBH,  b, 0, stream>>>(eidx, E, flags, shift, NB, bcnt);
    k_bscan <<<1,    b, 0, stream>>>(bcnt, bbase, NB, (int)E);
    k_bin   <<<gBN,  dim3(512), 0, stream>>>(eidx, E, ew, flags, shift, NB, bbase, gcur, csrTmp);
    k_bucket<<<NB,   dim3(1024), 0, stream>>>(csrTmp, bbase, shift, N, (int)E, csr, rowptr, dinv);
    // layer 1: zp1 = bf16(dinv*(x@W1))
    k_mm1   <<<gMM1, b, 0, stream>>>(x, W1, flags, dinv, 1, bufA, N, 1);
    // layer 1 pull fused with layer-2 transform: bufB = bf16(dinv*(relu(agg1+b1)@W2))
    k_pullT <<<gPull, b, 0, stream>>>(csr, rowptr, dinv, bufA, W2, b1, flags, bufB, N);
    // layer 2 pull fused with layer-3 transform: bufA = bf16(dinv*(relu(agg2+b2)@W3))
    k_pullT <<<gPull, b, 0, stream>>>(csr, rowptr, dinv, bufB, W3, b2, flags, bufA, N);
    // layer 3 pull (plain): bufB = agg3 (f32 for pooling)
    k_pull  <<<gPull, b, 0, stream>>>(csr, rowptr, dinv, bufA, bufB, N);
    // head: pool phase 1, then pool phase 2 + MLP (multi-block)
    k_pool1<<<gP1, b, 0, stream>>>(bufB, batch, flags, gacc, N);
    k_mlpG <<<(G+3)/4, b, 0, stream>>>(gacc, batch, b3, L1w, L1b, L2w, L2b, L3w, L3b, L4w, L4b,
                                       flags, d_out, N, G);
    return;
  }

  // ---- fallback: atomic-scatter path ----
  {
    float* wf    = (float*)d_ws;
    int*   flags = (int*)d_ws;
    size_t Npad  = ((size_t)N + 255) & ~(size_t)255;
    float* dinv  = wf + 64;
    float* nrm   = dinv + Npad;
    float* bufA  = nrm + E;
    float* bufB  = bufA + (size_t)N*32;
    float* gpool = bufB + (size_t)N*32;
    int gN32 = (N*32 + 255)/256;
    int gE32 = (int)((E*32 + 255)/256);

    k_sniff    <<<1,    b, 0, stream>>>(x, eidx, flags, (int*)nullptr, 0);
    k_init_deg <<<gN,   b, 0, stream>>>(dinv, N);
    k_deg_accum<<<gE,   b, 0, stream>>>(eidx, E, ew, flags, dinv);
    k_dinv     <<<gN,   b, 0, stream>>>(dinv, N);
    k_norm     <<<gE,   b, 0, stream>>>(eidx, E, ew, dinv, flags, nrm);
    k_mm1      <<<gMM1, b, 0, stream>>>(x, W1, flags, dinv, 0, bufA, N, 0);
    k_selfloop <<<gN32, b, 0, stream>>>(bufA, dinv, bufB, N);
    k_scatter  <<<gE32, b, 0, stream>>>(eidx, E, nrm, flags, bufA, bufB);
    k_mmh      <<<gMM,  b, 0, stream>>>(bufB, b1, 1, W2, flags, dinv, 0, bufA, N);
    k_selfloop <<<gN32, b, 0, stream>>>(bufA, dinv, bufB, N);
    k_scatter  <<<gE32, b, 0, stream>>>(eidx, E, nrm, flags, bufA, bufB);
    k_mmh      <<<gMM,  b, 0, stream>>>(bufB, b2, 1, W3, flags, dinv, 0, bufA, N);
    k_selfloop <<<gN32, b, 0, stream>>>(bufA, dinv, bufB, N);
    k_scatter  <<<gE32, b, 0, stream>>>(eidx, E, nrm, flags, bufA, bufB);
    k_pool<<<64, b, 0, stream>>>(bufB, b3, batch, flags, gpool, N);
    k_mlp <<<1,  b, 0, stream>>>(gpool, L1w, L1b, L2w, L2b, L3w, L3b, L4w, L4b, flags, d_out);
  }
}

// Round 14
// 438.880 us; speedup vs baseline: 1.0318x; 1.0318x over previous
//
#include <hip/hip_runtime.h>
#include <hip/hip_bf16.h>

typedef __hip_bfloat16 bf16;
typedef __attribute__((ext_vector_type(8))) short bf16x8;
typedef __attribute__((ext_vector_type(4))) float f32x4;

// ---------- dtype-adaptive loads (flags are wave-uniform) ----------
__device__ __forceinline__ float ldf(const void* p, long long i, int f32){
  return f32 ? ((const float*)p)[i] : __bfloat162float(((const bf16*)p)[i]);
}
__device__ __forceinline__ int ldi(const void* p, long long i, int i64){
  return i64 ? (int)((const long long*)p)[i] : ((const int*)p)[i];
}
// exact bf16x4 -> f32x4 unpack (shift<<16)
__device__ __forceinline__ float4 bf4_to_f4(ushort4 v){
  float4 r;
  r.x = __uint_as_float((unsigned)v.x << 16);
  r.y = __uint_as_float((unsigned)v.y << 16);
  r.z = __uint_as_float((unsigned)v.z << 16);
  r.w = __uint_as_float((unsigned)v.w << 16);
  return r;
}

// ---------- sniff input dtypes once per launch + zero scratch ----------
__global__ void k_sniff(const void* __restrict__ x, const void* __restrict__ eidx,
                        int* __restrict__ flags, int* __restrict__ zp, int nzero){
  __shared__ int s_f, s_i;
  if (threadIdx.x == 0){ s_f = 0; s_i = 0; }
  __syncthreads();
  int t = threadIdx.x;
  const unsigned short* u = (const unsigned short*)x;
  int hits = 0;
  for (int k = t; k < 2048; k += 256){
    unsigned short v = u[2*k];
    int e = (v >> 7) & 0xFF;
    if (e == 0xFF || e == 0x00) hits++;
  }
  if (hits) atomicAdd(&s_f, 1);
  const int* ii = (const int*)eidx;
  int nz = 0;
  for (int k = t; k < 1024; k += 256){ if (ii[2*k+1] != 0) nz++; }
  if (nz) atomicAdd(&s_i, 1);
  for (int i = t; i < nzero; i += 256) zp[i] = 0;
  __syncthreads();
  if (threadIdx.x == 0){
    flags[0] = s_f ? 1 : 0;   // 1 = float32, 0 = bf16
    flags[1] = s_i ? 0 : 1;   // 1 = int64,   0 = int32
  }
}

// ================= binned CSR build (shift=8: 256-node buckets) =================

__global__ void __launch_bounds__(256) k_bhist(const void* __restrict__ eidx, long long E,
                       const int* __restrict__ flags, int shift, int NB,
                       int* __restrict__ bcnt){
  __shared__ int h[1024];
  int t = threadIdx.x;
  for (int b = t; b < NB; b += 256) h[b] = 0;
  __syncthreads();
  int i64 = flags[1];
  long long e0 = (long long)blockIdx.x*4096;
  long long e1 = e0 + 4096; if (e1 > E) e1 = E;
  for (long long e = e0 + t; e < e1; e += 256){
    int d = ldi(eidx, E + e, i64);
    atomicAdd(&h[d >> shift], 1);
  }
  __syncthreads();
  for (int b = t; b < NB; b += 256) if (h[b]) atomicAdd(&bcnt[b], h[b]);
}

__global__ void __launch_bounds__(256) k_bscan(const int* __restrict__ bcnt, int* __restrict__ bbase,
                       int NB, int E){
  __shared__ int tmp[256];
  int t = threadIdx.x;
  int v0 = (4*t+0 < NB) ? bcnt[4*t+0] : 0;
  int v1 = (4*t+1 < NB) ? bcnt[4*t+1] : 0;
  int v2 = (4*t+2 < NB) ? bcnt[4*t+2] : 0;
  int v3 = (4*t+3 < NB) ? bcnt[4*t+3] : 0;
  int s = v0+v1+v2+v3;
  tmp[t] = s;
  __syncthreads();
  for (int st = 1; st < 256; st <<= 1){
    int add = (t >= st) ? tmp[t-st] : 0;
    __syncthreads();
    tmp[t] += add;
    __syncthreads();
  }
  int run = tmp[t] - s;
  if (4*t+0 < NB){ bbase[4*t+0] = run; run += v0; }
  if (4*t+1 < NB){ bbase[4*t+1] = run; run += v1; }
  if (4*t+2 < NB){ bbase[4*t+2] = run; run += v2; }
  if (4*t+3 < NB){ bbase[4*t+3] = run; run += v3; }
  if (t == 255) bbase[NB] = E;
}

// 4096-edge chunks, 512 threads; wave-level shfl scan; dst cached in regs (STATIC indexing)
#define BINCH 4096
__global__ void __launch_bounds__(512) k_bin(const void* __restrict__ eidx, long long E,
                     const void* __restrict__ ew, const int* __restrict__ flags,
                     int shift, int NB, const int* __restrict__ bbase,
                     int* __restrict__ gcur, int2* __restrict__ csrTmp){
  __shared__ int bst[512];
  __shared__ int bcur[512];
  __shared__ int gof[512];
  __shared__ int wtot[8];
  __shared__ int2 ent[BINCH];
  __shared__ unsigned short entb[BINCH];
  int t = threadIdx.x;
  int lane = t & 63, wv = t >> 6;
  int i64 = flags[1], f32 = flags[0];
  long long e0 = (long long)blockIdx.x*BINCH;
  int cnt = (int)(((E - e0) < BINCH) ? (E - e0) : BINCH);
  int msk = (1 << shift) - 1;
  for (int b = t; b < NB; b += 512) bst[b] = 0;
  __syncthreads();
  int dcache[8];                       // BINCH/512 == 8; compile-time indexed
  #pragma unroll
  for (int k = 0; k < 8; ++k){
    int i = t + k*512;
    if (i < cnt){
      int d = ldi(eidx, E + e0 + i, i64);
      dcache[k] = d;
      atomicAdd(&bst[d >> shift], 1);
    }
  }
  __syncthreads();
  int v = (t < NB) ? bst[t] : 0;
  // wave-level inclusive scan, then cross-wave combine (single barrier)
  int incl = v;
  #pragma unroll
  for (int st = 1; st < 64; st <<= 1){
    int u = __shfl_up(incl, st, 64);
    if (lane >= st) incl += u;
  }
  if (lane == 63) wtot[wv] = incl;
  __syncthreads();
  int wbase = 0;
  for (int i = 0; i < wv; ++i) wbase += wtot[i];
  int run = wbase + incl - v;       // exclusive prefix
  if (t < NB){
    bst[t] = run; bcur[t] = run;
    if (v) gof[t] = atomicAdd(&gcur[t], v);
  }
  __syncthreads();
  #pragma unroll
  for (int k = 0; k < 8; ++k){
    int i = t + k*512;
    if (i < cnt){
      int d  = dcache[k];
      int sc = ldi(eidx, e0 + i, i64);
      float w = ldf(ew, e0 + i, f32);
      int b = d >> shift;
      int dl = d & msk;
      int pos = atomicAdd(&bcur[b], 1);
      ent[pos]  = make_int2((dl << 24) | sc, __float_as_int(w));
      entb[pos] = (unsigned short)b;
    }
  }
  __syncthreads();
  for (int i = t; i < cnt; i += 512){
    int b = entb[i];
    int gpos = bbase[b] + gof[b] + (i - bst[b]);
    csrTmp[gpos] = ent[i];
  }
}

// per-bucket (1024 threads): counting sort by dst-low.
// Pass 1: ONE packed u64 LDS atomic per edge; first 10 records/thread cached in regs
// (STATIC indexing; dynamic tail reloads). Scan: wave shfl + combine.
__global__ void __launch_bounds__(1024) k_bucket(const int2* __restrict__ csrTmp, const int* __restrict__ bbase,
                        int shift, int N, int E, int2* __restrict__ csr,
                        int* __restrict__ rowptr, float* __restrict__ dinv){
  __shared__ unsigned long long hw[256];
  __shared__ int   st4[4];
  __shared__ int   cur[256];
  __shared__ float sdv[256];
  int b = blockIdx.x, t = threadIdx.x;
  int base = bbase[b], cnt = bbase[b+1] - base;
  if (t < 256) hw[t] = 0ull;
  __syncthreads();
  int2 pc[10];                         // compile-time indexed cache (covers cnt <= 10240)
  #pragma unroll
  for (int k = 0; k < 10; ++k){
    int i = t + k*1024;
    if (i < cnt){
      int2 p = csrTmp[base + i];
      pc[k] = p;
      int dl = ((unsigned)p.x) >> 24;
      float w = __int_as_float(p.y);
      unsigned long long pk = ((unsigned long long)1 << 40)
                            + (unsigned long long)__float2uint_rn(w * 65536.0f);
      atomicAdd(&hw[dl], pk);
    }
  }
  for (int i = t + 10*1024; i < cnt; i += 1024){
    int2 p = csrTmp[base + i];
    int dl = ((unsigned)p.x) >> 24;
    float w = __int_as_float(p.y);
    unsigned long long pk = ((unsigned long long)1 << 40)
                          + (unsigned long long)__float2uint_rn(w * 65536.0f);
    atomicAdd(&hw[dl], pk);
  }
  __syncthreads();
  int c = 0; float wsumv = 0.f;
  if (t < 256){
    unsigned long long vv = hw[t];
    c = (int)(vv >> 40);
    wsumv = (float)(vv & (((unsigned long long)1 << 40) - 1)) * (1.0f/65536.0f);
  }
  int lane = t & 63, wv = t >> 6;
  int incl = c;
  #pragma unroll
  for (int s2 = 1; s2 < 64; s2 <<= 1){
    int u = __shfl_up(incl, s2, 64);
    if (lane >= s2) incl += u;
  }
  if (t < 256 && lane == 63) st4[wv] = incl;
  __syncthreads();
  if (t < 256){
    int wbase = 0;
    for (int i = 0; i < wv; ++i) wbase += st4[i];
    int ex = wbase + incl - c;      // exclusive prefix
    cur[t] = ex;
    int n = (b << shift) + t;
    if (n < N){
      float deg = 1.f + wsumv;
      float di = (deg > 0.f) ? rsqrtf(fmaxf(deg, 1e-30f)) : 0.f;
      sdv[t] = di;
      dinv[n] = di;
      rowptr[n] = base + ex;
      if (n == N-1) rowptr[N] = E;
    }
  }
  __syncthreads();
  #pragma unroll
  for (int k = 0; k < 10; ++k){
    int i = t + k*1024;
    if (i < cnt){
      int2 p = pc[k];
      int dl = ((unsigned)p.x) >> 24;
      int pos = atomicAdd(&cur[dl], 1);
      float nm = __int_as_float(p.y) * sdv[dl];       // w * dinv[dst]
      csr[base + pos] = make_int2(p.x & 0xFFFFFF, __float_as_int(nm));
    }
  }
  for (int i = t + 10*1024; i < cnt; i += 1024){
    int2 p = csrTmp[base + i];
    int dl = ((unsigned)p.x) >> 24;
    int pos = atomicAdd(&cur[dl], 1);
    float nm = __int_as_float(p.y) * sdv[dl];
    csr[base + pos] = make_int2(p.x & 0xFFFFFF, __float_as_int(nm));
  }
}

// ---------- plain pull: wave/node, round-robin grid-stride, 4-deep ILP, bf16 zp ----------
// zp = bf16(dinv*(hW)); agg[n] = dinv[n]*zp[n] + sum csr.y*zp[src]   (f32 out for pool)
__global__ void __launch_bounds__(256) k_pull(const int2* __restrict__ csr, const int* __restrict__ rowptr,
                       const float* __restrict__ dinv, const void* __restrict__ zp,
                       float* __restrict__ agg, int N){
  int lane = threadIdx.x & 63;
  int g = lane >> 3;            // edge subgroup 0..7
  int q = lane & 7;             // feature quad 0..7
  const ushort4* h4 = (const ushort4*)zp;   // 8 x ushort4 per 64B row
  int nwaves = gridDim.x*4;
  for (int n = blockIdx.x*4 + (threadIdx.x >> 6); n < N; n += nwaves){
    int s0 = rowptr[n], s1 = rowptr[n+1];
    float4 acc = make_float4(0.f,0.f,0.f,0.f);
    if (g == 0){
      float di = dinv[n];
      float4 hv = bf4_to_f4(h4[n*8 + q]);
      acc.x = di*hv.x; acc.y = di*hv.y; acc.z = di*hv.z; acc.w = di*hv.w;
    }
    int j = s0 + g;
    for (; j + 24 < s1; j += 32){
      int2 p0 = csr[j];
      int2 p1 = csr[j+8];
      int2 p2 = csr[j+16];
      int2 p3 = csr[j+24];
      float4 h0 = bf4_to_f4(h4[(p0.x<<3)+q]);
      float4 h1 = bf4_to_f4(h4[(p1.x<<3)+q]);
      float4 h2 = bf4_to_f4(h4[(p2.x<<3)+q]);
      float4 h3 = bf4_to_f4(h4[(p3.x<<3)+q]);
      float n0 = __int_as_float(p0.y), n1 = __int_as_float(p1.y);
      float n2 = __int_as_float(p2.y), n3 = __int_as_float(p3.y);
      acc.x = fmaf(n0, h0.x, acc.x); acc.y = fmaf(n0, h0.y, acc.y);
      acc.z = fmaf(n0, h0.z, acc.z); acc.w = fmaf(n0, h0.w, acc.w);
      acc.x = fmaf(n1, h1.x, acc.x); acc.y = fmaf(n1, h1.y, acc.y);
      acc.z = fmaf(n1, h1.z, acc.z); acc.w = fmaf(n1, h1.w, acc.w);
      acc.x = fmaf(n2, h2.x, acc.x); acc.y = fmaf(n2, h2.y, acc.y);
      acc.z = fmaf(n2, h2.z, acc.z); acc.w = fmaf(n2, h2.w, acc.w);
      acc.x = fmaf(n3, h3.x, acc.x); acc.y = fmaf(n3, h3.y, acc.y);
      acc.z = fmaf(n3, h3.z, acc.z); acc.w = fmaf(n3, h3.w, acc.w);
    }
    if (j + 8 < s1){
      int2 p0 = csr[j];
      int2 p1 = csr[j+8];
      float4 h0 = bf4_to_f4(h4[(p0.x<<3)+q]);
      float4 h1 = bf4_to_f4(h4[(p1.x<<3)+q]);
      float n0 = __int_as_float(p0.y), n1 = __int_as_float(p1.y);
      acc.x = fmaf(n0, h0.x, acc.x); acc.y = fmaf(n0, h0.y, acc.y);
      acc.z = fmaf(n0, h0.z, acc.z); acc.w = fmaf(n0, h0.w, acc.w);
      acc.x = fmaf(n1, h1.x, acc.x); acc.y = fmaf(n1, h1.y, acc.y);
      acc.z = fmaf(n1, h1.z, acc.z); acc.w = fmaf(n1, h1.w, acc.w);
      j += 16;
    }
    if (j < s1){
      int2 p = csr[j];
      float nm = __int_as_float(p.y);
      float4 hv = bf4_to_f4(h4[(p.x<<3)+q]);
      acc.x = fmaf(nm, hv.x, acc.x); acc.y = fmaf(nm, hv.y, acc.y);
      acc.z = fmaf(nm, hv.z, acc.z); acc.w = fmaf(nm, hv.w, acc.w);
    }
    #pragma unroll
    for (int st = 8; st < 64; st <<= 1){
      acc.x += __shfl_xor(acc.x, st, 64);
      acc.y += __shfl_xor(acc.y, st, 64);
      acc.z += __shfl_xor(acc.z, st, 64);
      acc.w += __shfl_xor(acc.w, st, 64);
    }
    if (g == 0) ((float4*)agg)[n*8 + q] = acc;
  }
}

// ---------- fused pull + next-layer transform (round-robin grid-stride, wave-private LDS epilogue) ----------
// out[n] = bf16( dinv[n] * ( relu(agg[n] + b_prev) @ W_next ) )   [32x32 GEMV per node]
__global__ void __launch_bounds__(256) k_pullT(const int2* __restrict__ csr, const int* __restrict__ rowptr,
                        const float* __restrict__ dinv, const void* __restrict__ zp,
                        const void* __restrict__ Wn, const void* __restrict__ bn,
                        const int* __restrict__ flags,
                        void* __restrict__ out, int N){
  __shared__ float  ws[32*32];   // W_next [k][f]
  __shared__ float4 bs4[8];      // bias (32 f)
  __shared__ float4 sT4[4][8];   // per-wave t = relu(agg+b), wave-private slot
  int tid = threadIdx.x;
  int f32 = flags[0];
  for (int i = tid; i < 1024; i += 256) ws[i] = ldf(Wn, i, f32);
  if (tid < 32) ((float*)bs4)[tid] = ldf(bn, tid, f32);
  __syncthreads();              // only barrier: uniform-cost weight preload

  int lane = tid & 63;
  int wave = tid >> 6;
  int g = lane >> 3;            // edge subgroup 0..7
  int q = lane & 7;             // feature quad 0..7
  int f  = lane & 31;
  int hh = lane >> 5;
  const ushort4* h4 = (const ushort4*)zp;
  const float4* tr4 = &sT4[wave][hh*4];
  int nwaves = gridDim.x*4;
  for (int n = blockIdx.x*4 + wave; n < N; n += nwaves){
    int s0 = rowptr[n], s1 = rowptr[n+1];
    float din = dinv[n];
    float4 acc = make_float4(0.f,0.f,0.f,0.f);
    if (g == 0){
      float4 hv = bf4_to_f4(h4[n*8 + q]);
      acc.x = din*hv.x; acc.y = din*hv.y; acc.z = din*hv.z; acc.w = din*hv.w;
    }
    int j = s0 + g;
    for (; j + 24 < s1; j += 32){
      int2 p0 = csr[j];
      int2 p1 = csr[j+8];
      int2 p2 = csr[j+16];
      int2 p3 = csr[j+24];
      float4 h0 = bf4_to_f4(h4[(p0.x<<3)+q]);
      float4 h1 = bf4_to_f4(h4[(p1.x<<3)+q]);
      float4 h2 = bf4_to_f4(h4[(p2.x<<3)+q]);
      float4 h3 = bf4_to_f4(h4[(p3.x<<3)+q]);
      float n0 = __int_as_float(p0.y), n1 = __int_as_float(p1.y);
      float n2 = __int_as_float(p2.y), n3 = __int_as_float(p3.y);
      acc.x = fmaf(n0, h0.x, acc.x); acc.y = fmaf(n0, h0.y, acc.y);
      acc.z = fmaf(n0, h0.z, acc.z); acc.w = fmaf(n0, h0.w, acc.w);
      acc.x = fmaf(n1, h1.x, acc.x); acc.y = fmaf(n1, h1.y, acc.y);
      acc.z = fmaf(n1, h1.z, acc.z); acc.w = fmaf(n1, h1.w, acc.w);
      acc.x = fmaf(n2, h2.x, acc.x); acc.y = fmaf(n2, h2.y, acc.y);
      acc.z = fmaf(n2, h2.z, acc.z); acc.w = fmaf(n2, h2.w, acc.w);
      acc.x = fmaf(n3, h3.x, acc.x); acc.y = fmaf(n3, h3.y, acc.y);
      acc.z = fmaf(n3, h3.z, acc.z); acc.w = fmaf(n3, h3.w, acc.w);
    }
    if (j + 8 < s1){
      int2 p0 = csr[j];
      int2 p1 = csr[j+8];
      float4 h0 = bf4_to_f4(h4[(p0.x<<3)+q]);
      float4 h1 = bf4_to_f4(h4[(p1.x<<3)+q]);
      float n0 = __int_as_float(p0.y), n1 = __int_as_float(p1.y);
      acc.x = fmaf(n0, h0.x, acc.x); acc.y = fmaf(n0, h0.y, acc.y);
      acc.z = fmaf(n0, h0.z, acc.z); acc.w = fmaf(n0, h0.w, acc.w);
      acc.x = fmaf(n1, h1.x, acc.x); acc.y = fmaf(n1, h1.y, acc.y);
      acc.z = fmaf(n1, h1.z, acc.z); acc.w = fmaf(n1, h1.w, acc.w);
      j += 16;
    }
    if (j < s1){
      int2 p = csr[j];
      float nm = __int_as_float(p.y);
      float4 hv = bf4_to_f4(h4[(p.x<<3)+q]);
      acc.x = fmaf(nm, hv.x, acc.x); acc.y = fmaf(nm, hv.y, acc.y);
      acc.z = fmaf(nm, hv.z, acc.z); acc.w = fmaf(nm, hv.w, acc.w);
    }
    #pragma unroll
    for (int st = 8; st < 64; st <<= 1){
      acc.x += __shfl_xor(acc.x, st, 64);
      acc.y += __shfl_xor(acc.y, st, 64);
      acc.z += __shfl_xor(acc.z, st, 64);
      acc.w += __shfl_xor(acc.w, st, 64);
    }
    // t = relu(agg + b_prev) staged to this wave's private LDS row (no barrier needed)
    if (g == 0){
      float4 b4 = bs4[q];
      float4 t;
      t.x = fmaxf(acc.x + b4.x, 0.f);
      t.y = fmaxf(acc.y + b4.y, 0.f);
      t.z = fmaxf(acc.z + b4.z, 0.f);
      t.w = fmaxf(acc.w + b4.w, 0.f);
      sT4[wave][q] = t;
    }
    // 32x32 GEMV: lane (f, hh) does k in [16*hh, 16*hh+16).
    float s = 0.f;
    #pragma unroll
    for (int i = 0; i < 4; ++i){
      float4 tv = tr4[i];
      int k = hh*16 + i*4;
      s = fmaf(tv.x, ws[(k+0)*32 + f], s);
      s = fmaf(tv.y, ws[(k+1)*32 + f], s);
      s = fmaf(tv.z, ws[(k+2)*32 + f], s);
      s = fmaf(tv.w, ws[(k+3)*32 + f], s);
    }
    s += __shfl_xor(s, 32, 64);
    if (hh == 0) ((bf16*)out)[n*32 + f] = __float2bfloat16(din * s);
  }
}

// ---------- layer-1 matmul ----------
__global__ void __launch_bounds__(256) k_mm1(const void* __restrict__ x, const void* __restrict__ W,
                      const int* __restrict__ flags, const float* __restrict__ dinv,
                      int mul_dinv, void* __restrict__ out, int N, int out_bf16){
  __shared__ float Ws[128*32];
  __shared__ float xs[32*128];
  int f32 = flags[0];
  float* out_f = (float*)out;
  bf16*  out_h = (bf16*)out;
  if (!f32){
    int wave = threadIdx.x >> 6;
    int lane = threadIdx.x & 63;
    int m = lane & 15, quad = lane >> 4;
    long long tile = (long long)blockIdx.x*4 + wave;
    int row0 = (int)(tile*16);
    if (row0 >= N) return;
    const short* xp = (const short*)x;
    const short* wp = (const short*)W;
    int row = row0 + m;
    bool rv = row < N;
    bf16x8 a[4];
    #pragma unroll
    for (int kc = 0; kc < 4; ++kc){
      if (rv) a[kc] = *(const bf16x8*)(xp + (long long)row*128 + kc*32 + quad*8);
      else    a[kc] = (bf16x8)(short)0;
    }
    #pragma unroll
    for (int nt = 0; nt < 2; ++nt){
      f32x4 acc = {0.f,0.f,0.f,0.f};
      #pragma unroll
      for (int kc = 0; kc < 4; ++kc){
        bf16x8 bfr;
        #pragma unroll
        for (int j = 0; j < 8; ++j)
          bfr[j] = wp[(kc*32 + quad*8 + j)*32 + nt*16 + m];
        acc = __builtin_amdgcn_mfma_f32_16x16x32_bf16(a[kc], bfr, acc, 0, 0, 0);
      }
      #pragma unroll
      for (int r = 0; r < 4; ++r){
        int rr = row0 + quad*4 + r;
        if (rr < N){
          float v = acc[r];
          if (mul_dinv) v *= dinv[rr];
          long long idx = (long long)rr*32 + nt*16 + m;
          if (out_bf16) out_h[idx] = __float2bfloat16(v);
          else          out_f[idx] = v;
        }
      }
    }
    return;
  }
  // ---- f32 fallback (legacy) ----
  int tid = threadIdx.x;
  for (int i = tid; i < 4096; i += 256) Ws[i] = ((const float*)W)[i];
  int n0 = blockIdx.x*32;
  for (int i = tid; i < 4096; i += 256){
    int r = i >> 7, k = i & 127, n = n0 + r;
    xs[i] = (n < N) ? ((const float*)x)[(long long)n*128 + k] : 0.f;
  }
  __syncthreads();
  int f = tid & 31, r = tid >> 5;
  float a0=0.f, a1=0.f, a2=0.f, a3=0.f;
  for (int k = 0; k < 128; ++k){
    float w = Ws[k*32+f];
    a0 = fmaf(xs[(r    )*128+k], w, a0);
    a1 = fmaf(xs[(r+ 8)*128+k], w, a1);
    a2 = fmaf(xs[(r+16)*128+k], w, a2);
    a3 = fmaf(xs[(r+24)*128+k], w, a3);
  }
  #pragma unroll 4
  for (int rr = 0; rr < 4; ++rr){
    int n = n0 + r + rr*8;
    float v = (rr==0)?a0:(rr==1)?a1:(rr==2)?a2:a3;
    if (n < N){
      if (mul_dinv) v *= dinv[n];
      if (out_bf16) out_h[n*32+f] = __float2bfloat16(v);
      else          out_f[n*32+f] = v;
    }
  }
}

// ---------- hidden matmul (fallback path only) ----------
__global__ void k_mmh(const float* __restrict__ in, const void* __restrict__ bias, int do_relu,
                      const void* __restrict__ W, const int* __restrict__ flags,
                      const float* __restrict__ dinv, int mul_dinv,
                      float* __restrict__ out, int N){
  __shared__ float Wt[32*36];
  __shared__ float xs[32*32];
  int tid = threadIdx.x;
  int f32 = flags[0];
  for (int i = tid; i < 1024; i += 256){
    int k = i >> 5, f = i & 31;
    Wt[f*36 + k] = ldf(W, i, f32);
  }
  int n0 = blockIdx.x*32;
  for (int i = tid; i < 1024; i += 256){
    int r = i >> 5, k = i & 31, n = n0 + r;
    float v = 0.f;
    if (n < N){
      v = in[(long long)n*32+k] + ldf(bias, k, f32);
      if (do_relu) v = fmaxf(v, 0.f);
    }
    xs[i] = v;
  }
  __syncthreads();
  int f = tid & 31, r = tid >> 5;
  const float4* xs4 = (const float4*)xs;
  float a0=0.f, a1=0.f, a2=0.f, a3=0.f;
  #pragma unroll
  for (int kc = 0; kc < 8; ++kc){
    float4 wv = *(const float4*)&Wt[f*36 + kc*4];
    float4 x0 = xs4[(r    )*8 + kc];
    float4 x1 = xs4[(r+ 8)*8 + kc];
    float4 x2 = xs4[(r+16)*8 + kc];
    float4 x3 = xs4[(r+24)*8 + kc];
    a0 = fmaf(x0.x,wv.x,fmaf(x0.y,wv.y,fmaf(x0.z,wv.z,fmaf(x0.w,wv.w,a0))));
    a1 = fmaf(x1.x,wv.x,fmaf(x1.y,wv.y,fmaf(x1.z,wv.z,fmaf(x1.w,wv.w,a1))));
    a2 = fmaf(x2.x,wv.x,fmaf(x2.y,wv.y,fmaf(x2.z,wv.z,fmaf(x2.w,wv.w,a2))));
    a3 = fmaf(x3.x,wv.x,fmaf(x3.y,wv.y,fmaf(x3.z,wv.z,fmaf(x3.w,wv.w,a3))));
  }
  int n;
  n = n0+r;    if (n < N) out[n*32+f] = mul_dinv ? a0*dinv[n] : a0;
  n = n0+r+8;  if (n < N) out[n*32+f] = mul_dinv ? a1*dinv[n] : a1;
  n = n0+r+16; if (n < N) out[n*32+f] = mul_dinv ? a2*dinv[n] : a2;
  n = n0+r+24; if (n < N) out[n*32+f] = mul_dinv ? a3*dinv[n] : a3;
}

// ---------- two-phase mean pool ----------
__device__ __forceinline__ int lower_bound_i(const void* __restrict__ a, int n, int v, int i64){
  int lo = 0, hi = n;
  while (lo < hi){ int mid = (lo+hi) >> 1; if (ldi(a, mid, i64) < v) lo = mid+1; else hi = mid; }
  return lo;
}

// phase 1: 128 rows/block; running accumulator per thread, flush on graph change
__global__ void k_pool1(const float* __restrict__ agg, const void* __restrict__ batch,
                        const int* __restrict__ flags, float* __restrict__ gacc, int N){
  int i64 = flags[1];
  int f = threadIdx.x & 31, r = threadIdx.x >> 5;
  long long start = (long long)blockIdx.x*128;
  long long end = start + 128; if (end > N) end = N;
  float acc = 0.f; int curg = -1;
  for (long long n = start + r; n < end; n += 8){
    int g = ldi(batch, n, i64);
    if (g != curg){
      if (curg >= 0) atomicAdd(&gacc[curg*32 + f], acc);
      acc = 0.f; curg = g;
    }
    acc += agg[n*32 + f];
  }
  if (curg >= 0) atomicAdd(&gacc[curg*32 + f], acc);
}

// legacy single-phase pool (fallback path)
__global__ void k_pool(const float* __restrict__ agg, const void* __restrict__ b3,
                       const void* __restrict__ batch, const int* __restrict__ flags,
                       float* __restrict__ gpool, int N){
  int f32 = flags[0], i64 = flags[1];
  int g = blockIdx.x;
  int start = lower_bound_i(batch, N, g, i64);
  int end   = lower_bound_i(batch, N, g+1, i64);
  int tid = threadIdx.x;
  int f = tid & 31, r = tid >> 5;
  float acc = 0.f;
  for (int n = start + r; n < end; n += 8) acc += agg[n*32+f];
  __shared__ float red[8][32];
  red[r][f] = acc;
  __syncthreads();
  if (r == 0){
    float s = red[0][f];
    #pragma unroll
    for (int j = 1; j < 8; ++j) s += red[j][f];
    int c = end - start;
    float gv = (c > 0) ? (s / (float)c + ldf(b3, f, f32)) : 0.f;
    gpool[g*32+f] = gv;
  }
}

// ---------- multi-block MLP head: (G+3)/4 blocks, 4 graphs/block ----------
__global__ void __launch_bounds__(256) k_mlpG(const float* __restrict__ gacc,
                      const void* __restrict__ batch, const void* __restrict__ b3,
                      const void* __restrict__ L1w, const void* __restrict__ L1b,
                      const void* __restrict__ L2w, const void* __restrict__ L2b,
                      const void* __restrict__ L3w, const void* __restrict__ L3b,
                      const void* __restrict__ L4w, const void* __restrict__ L4b,
                      const int* __restrict__ flags, void* __restrict__ out, int N, int G){
  __shared__ float ws1[32*64];
  __shared__ float ws2[64*64];
  __shared__ float ws3[64*64];
  __shared__ float ws4[64*10];
  __shared__ float wb1[64], wb2[64], wb3[64], wb4[10], b3s[32];
  __shared__ float gin[4*32];
  __shared__ float A[4*64];
  __shared__ float B[4*64];
  __shared__ int   sb[5];
  int tid = threadIdx.x;
  int f32 = flags[0], i64 = flags[1];
  int g0 = blockIdx.x*4;

  // one parallel burst: all weights + biases + graph bounds
  for (int i = tid; i < 2048; i += 256) ws1[i] = ldf(L1w, i, f32);
  for (int i = tid; i < 4096; i += 256) ws2[i] = ldf(L2w, i, f32);
  for (int i = tid; i < 4096; i += 256) ws3[i] = ldf(L3w, i, f32);
  for (int i = tid; i < 640;  i += 256) ws4[i] = ldf(L4w, i, f32);
  if (tid < 64) wb1[tid] = ldf(L1b, tid, f32);
  else if (tid >= 64 && tid < 128) wb2[tid-64] = ldf(L2b, tid-64, f32);
  else if (tid >= 128 && tid < 192) wb3[tid-128] = ldf(L3b, tid-128, f32);
  else if (tid >= 192 && tid < 202) wb4[tid-192] = ldf(L4b, tid-192, f32);
  else if (tid >= 224) b3s[tid-224] = ldf(b3, tid-224, f32);
  if (tid >= 202 && tid < 207){
    int gg = g0 + (tid - 202);
    sb[tid-202] = (gg <= G) ? lower_bound_i(batch, N, gg, i64) : N;
  }
  __syncthreads();
  // pool phase 2 for this block's 4 graphs
  for (int i = tid; i < 128; i += 256){
    int g = i >> 5, f = i & 31;
    int gg = g0 + g;
    float v = 0.f;
    if (gg < G){
      int c = sb[g+1] - sb[g];
      v = (c > 0) ? gacc[gg*32 + f]/(float)c + b3s[f] : 0.f;
    }
    gin[i] = v;
  }
  __syncthreads();
  // L1: 32 -> 64, relu
  {
    int g = tid >> 6, j = tid & 63;
    float a = wb1[j];
    #pragma unroll
    for (int k = 0; k < 32; ++k) a = fmaf(gin[g*32+k], ws1[k*64+j], a);
    A[g*64+j] = fmaxf(a, 0.f);
  }
  __syncthreads();
  // L2: 64 -> 64, relu
  {
    int g = tid >> 6, j = tid & 63;
    float a = wb2[j];
    #pragma unroll
    for (int k = 0; k < 64; ++k) a = fmaf(A[g*64+k], ws2[k*64+j], a);
    B[g*64+j] = fmaxf(a, 0.f);
  }
  __syncthreads();
  // L3: 64 -> 64, relu
  {
    int g = tid >> 6, j = tid & 63;
    float a = wb3[j];
    #pragma unroll
    for (int k = 0; k < 64; ++k) a = fmaf(B[g*64+k], ws3[k*64+j], a);
    A[g*64+j] = fmaxf(a, 0.f);
  }
  __syncthreads();
  // L4: 64 -> 10
  if (tid < 40){
    int g = tid / 10, c = tid % 10;
    int gg = g0 + g;
    if (gg < G){
      float a = wb4[c];
      #pragma unroll
      for (int k = 0; k < 64; ++k) a = fmaf(A[g*64+k], ws4[k*10+c], a);
      if (f32) ((float*)out)[gg*10+c] = a;
      else     ((bf16*)out)[gg*10+c]  = __float2bfloat16(a);
    }
  }
}

// ---------- legacy MLP head (fallback path) ----------
__global__ void __launch_bounds__(256, 1) k_mlp(const float* __restrict__ gpool,
                      const void* __restrict__ L1w, const void* __restrict__ L1b,
                      const void* __restrict__ L2w, const void* __restrict__ L2b,
                      const void* __restrict__ L3w, const void* __restrict__ L3b,
                      const void* __restrict__ L4w, const void* __restrict__ L4b,
                      const int* __restrict__ flags, void* __restrict__ out){
  __shared__ float gin[64*32];
  __shared__ float A[64*65];
  __shared__ float B[64*65];
  __shared__ float ws[64*64];
  __shared__ float wb[64];
  int tid = threadIdx.x;
  int f32 = flags[0];
  int j  = tid & 63;
  int i0 = tid >> 6;
  float acc[16];

  for (int i = tid; i < 64*32; i += 256) gin[i] = gpool[i];
  for (int i = tid; i < 2048; i += 256) ws[i] = ldf(L1w, i, f32);
  if (tid < 64) wb[tid] = ldf(L1b, tid, f32);
  __syncthreads();
  #pragma unroll
  for (int r = 0; r < 16; ++r) acc[r] = wb[j];
  for (int k = 0; k < 32; ++k){
    float w = ws[k*64+j];
    #pragma unroll
    for (int r = 0; r < 16; ++r) acc[r] = fmaf(gin[(i0+4*r)*32+k], w, acc[r]);
  }
  #pragma unroll
  for (int r = 0; r < 16; ++r) A[(i0+4*r)*65+j] = fmaxf(acc[r], 0.f);
  __syncthreads();
  for (int i = tid; i < 4096; i += 256) ws[i] = ldf(L2w, i, f32);
  if (tid < 64) wb[tid] = ldf(L2b, tid, f32);
  __syncthreads();
  #pragma unroll
  for (int r = 0; r < 16; ++r) acc[r] = wb[j];
  for (int k = 0; k < 64; ++k){
    float w = ws[k*64+j];
    #pragma unroll
    for (int r = 0; r < 16; ++r) acc[r] = fmaf(A[(i0+4*r)*65+k], w, acc[r]);
  }
  #pragma unroll
  for (int r = 0; r < 16; ++r) B[(i0+4*r)*65+j] = fmaxf(acc[r], 0.f);
  __syncthreads();
  for (int i = tid; i < 4096; i += 256) ws[i] = ldf(L3w, i, f32);
  if (tid < 64) wb[tid] = ldf(L3b, tid, f32);
  __syncthreads();
  #pragma unroll
  for (int r = 0; r < 16; ++r) acc[r] = wb[j];
  for (int k = 0; k < 64; ++k){
    float w = ws[k*64+j];
    #pragma unroll
    for (int r = 0; r < 16; ++r) acc[r] = fmaf(B[(i0+4*r)*65+k], w, acc[r]);
  }
  #pragma unroll
  for (int r = 0; r < 16; ++r) A[(i0+4*r)*65+j] = fmaxf(acc[r], 0.f);
  __syncthreads();
  for (int i = tid; i < 640; i += 256) ws[i] = ldf(L4w, i, f32);
  if (tid < 10) wb[tid] = ldf(L4b, tid, f32);
  __syncthreads();
  if (tid < 64){
    int row = tid;
    float a10[10];
    #pragma unroll
    for (int c = 0; c < 10; ++c) a10[c] = wb[c];
    for (int k = 0; k < 64; ++k){
      float av = A[row*65+k];
      #pragma unroll
      for (int c = 0; c < 10; ++c) a10[c] = fmaf(av, ws[k*10+c], a10[c]);
    }
    #pragma unroll
    for (int c = 0; c < 10; ++c){
      if (f32) ((float*)out)[row*10+c] = a10[c];
      else     ((bf16*)out)[row*10+c]  = __float2bfloat16(a10[c]);
    }
  }
}

// ---------- fallback (atomic-scatter path, small ws) ----------
__global__ void k_init_deg(float* __restrict__ deg, int N){
  int i = blockIdx.x*256 + threadIdx.x;
  if (i < N) deg[i] = 1.0f;
}
__global__ void k_deg_accum(const void* __restrict__ eidx, long long E,
                            const void* __restrict__ w, const int* __restrict__ flags,
                            float* __restrict__ deg){
  long long e = (long long)blockIdx.x*256 + threadIdx.x;
  if (e < E){
    int f32 = flags[0], i64 = flags[1];
    atomicAdd(&deg[ldi(eidx, E + e, i64)], ldf(w, e, f32));
  }
}
__global__ void k_dinv(float* __restrict__ deg, int N){
  int i = blockIdx.x*256 + threadIdx.x;
  if (i < N){
    float d = deg[i];
    deg[i] = (d > 0.f) ? rsqrtf(fmaxf(d, 1e-30f)) : 0.f;
  }
}
__global__ void k_norm(const void* __restrict__ eidx, long long E,
                       const void* __restrict__ w, const float* __restrict__ dinv,
                       const int* __restrict__ flags, float* __restrict__ nrm){
  long long e = (long long)blockIdx.x*256 + threadIdx.x;
  if (e < E){
    int f32 = flags[0], i64 = flags[1];
    int s = ldi(eidx, e, i64), d = ldi(eidx, E + e, i64);
    nrm[e] = dinv[s] * ldf(w, e, f32) * dinv[d];
  }
}
__global__ void k_selfloop(const float* __restrict__ hlin, const float* __restrict__ dinv,
                           float* __restrict__ agg, int N){
  int idx = blockIdx.x*256 + threadIdx.x;
  if (idx < N*32){
    int n = idx >> 5;
    float di = dinv[n];
    agg[idx] = di*di*hlin[idx];
  }
}
__global__ void k_scatter(const void* __restrict__ eidx, long long E,
                          const float* __restrict__ nrm, const int* __restrict__ flags,
                          const float* __restrict__ hlin, float* __restrict__ agg){
  long long idx = (long long)blockIdx.x*256 + threadIdx.x;
  if (idx < E*32){
    int i64 = flags[1];
    long long e = idx >> 5;
    int f = (int)(idx & 31);
    int s = ldi(eidx, e, i64), d = ldi(eidx, E + e, i64);
    atomicAdd(&agg[(long long)d*32 + f], nrm[e] * hlin[(long long)s*32 + f]);
  }
}

extern "C" void kernel_launch(void* const* d_in, const int* in_sizes, int n_in,
                              void* d_out, int out_size, void* d_ws, size_t ws_size,
                              hipStream_t stream){
  const void* x   = d_in[0];
  const void* ew  = d_in[1];
  const void* W1  = d_in[2];
  const void* b1  = d_in[3];
  const void* W2  = d_in[4];
  const void* b2  = d_in[5];
  const void* W3  = d_in[6];
  const void* b3  = d_in[7];
  const void* L1w = d_in[8];  const void* L1b = d_in[9];
  const void* L2w = d_in[10]; const void* L2b = d_in[11];
  const void* L3w = d_in[12]; const void* L3b = d_in[13];
  const void* L4w = d_in[14]; const void* L4b = d_in[15];
  const void* eidx  = d_in[16];
  const void* batch = d_in[17];
  const long long E = in_sizes[1];
  const int N = in_sizes[17];
  const int G = out_size / 10;

  dim3 b(256);
  int gN   = (N + 255)/256;
  int gE   = (int)((E + 255)/256);
  int gMM  = (N + 31)/32;
  int gMM1 = (N + 63)/64;
  int gNd4 = (N + 3)/4;
  int gPull = gNd4 < 2048 ? gNd4 : 2048;   // round-robin grid-stride: ~8 blocks/CU
  int gBH  = (int)((E + 4095)/4096);
  int gBN  = (int)((E + BINCH - 1)/BINCH);
  int gP1  = (N + 127)/128;

  const int shift = 8;                       // 256-node buckets
  int NB = (N + 255) >> 8;

  auto AL = [](size_t v){ return (v + 255) & ~(size_t)255; };

  char* base = (char*)d_ws;
  size_t off = 0;
  size_t o_flags = off; off += AL(64*4);
  size_t o_rowp  = off; off += AL((size_t)(N+1)*4);
  size_t o_dinv  = off; off += AL((size_t)N*4);
  size_t o_bbase = off; off += AL((size_t)(NB+1)*4);
  size_t o_bcnt  = off; off += AL((size_t)NB*4) + AL((size_t)NB*4) + AL((size_t)G*32*4);  // bcnt+gcur+gacc
  size_t o_csr   = off; off += AL((size_t)E*8);
  size_t o_tmp   = off; off += AL((size_t)E*8);
  size_t o_bufA  = off; off += AL((size_t)N*128);
  size_t o_bufB  = off; off += AL((size_t)N*128);
  size_t o_gp    = off; off += AL((size_t)G*32*4);
  size_t needed  = off;

  if (ws_size >= needed && NB <= 512 && N < (1<<24) && G <= 64){
    int*   flags  = (int*)(base + o_flags);
    int*   rowptr = (int*)(base + o_rowp);
    float* dinv   = (float*)(base + o_dinv);
    int*   bbase  = (int*)(base + o_bbase);
    int*   bcnt   = (int*)(base + o_bcnt);
    int*   gcur   = (int*)(base + o_bcnt + AL((size_t)NB*4));
    float* gacc   = (float*)(base + o_bcnt + AL((size_t)NB*4) + AL((size_t)NB*4));
    int2*  csr    = (int2*)(base + o_csr);
    int2*  csrTmp = (int2*)(base + o_tmp);
    float* bufA   = (float*)(base + o_bufA);
    float* bufB   = (float*)(base + o_bufB);

    int nzero = (int)((AL((size_t)NB*4) + AL((size_t)NB*4))/4) + G*32;  // bcnt+gcur+gacc contiguous
    k_sniff <<<1,    b, 0, stream>>>(x, eidx, flags, bcnt, nzero);
    k_bhist <<<gBH,  b, 0, stream>>>(eidx, E, flags, shift, NB, bcnt);
    k_bscan <<<1,    b, 0, stream>>>(bcnt, bbase, NB, (int)E);
    k_bin   <<<gBN,  dim3(512), 0, stream>>>(eidx, E, ew, flags, shift, NB, bbase, gcur, csrTmp);
    k_bucket<<<NB,   dim3(1024), 0, stream>>>(csrTmp, bbase, shift, N, (int)E, csr, rowptr, dinv);
    // layer 1: zp1 = bf16(dinv*(x@W1))
    k_mm1   <<<gMM1, b, 0, stream>>>(x, W1, flags, dinv, 1, bufA, N, 1);
    // layer 1 pull fused with layer-2 transform: bufB = bf16(dinv*(relu(agg1+b1)@W2))
    k_pullT <<<gPull, b, 0, stream>>>(csr, rowptr, dinv, bufA, W2, b1, flags, bufB, N);
    // layer 2 pull fused with layer-3 transform: bufA = bf16(dinv*(relu(agg2+b2)@W3))
    k_pullT <<<gPull, b, 0, stream>>>(csr, rowptr, dinv, bufB, W3, b2, flags, bufA, N);
    // layer 3 pull (plain): bufB = agg3 (f32 for pooling)
    k_pull  <<<gPull, b, 0, stream>>>(csr, rowptr, dinv, bufA, bufB, N);
    // head: pool phase 1, then pool phase 2 + MLP (multi-block)
    k_pool1<<<gP1, b, 0, stream>>>(bufB, batch, flags, gacc, N);
    k_mlpG <<<(G+3)/4, b, 0, stream>>>(gacc, batch, b3, L1w, L1b, L2w, L2b, L3w, L3b, L4w, L4b,
                                       flags, d_out, N, G);
    return;
  }

  // ---- fallback: atomic-scatter path ----
  {
    float* wf    = (float*)d_ws;
    int*   flags = (int*)d_ws;
    size_t Npad  = ((size_t)N + 255) & ~(size_t)255;
    float* dinv  = wf + 64;
    float* nrm   = dinv + Npad;
    float* bufA  = nrm + E;
    float* bufB  = bufA + (size_t)N*32;
    float* gpool = bufB + (size_t)N*32;
    int gN32 = (N*32 + 255)/256;
    int gE32 = (int)((E*32 + 255)/256);

    k_sniff    <<<1,    b, 0, stream>>>(x, eidx, flags, (int*)nullptr, 0);
    k_init_deg <<<gN,   b, 0, stream>>>(dinv, N);
    k_deg_accum<<<gE,   b, 0, stream>>>(eidx, E, ew, flags, dinv);
    k_dinv     <<<gN,   b, 0, stream>>>(dinv, N);
    k_norm     <<<gE,   b, 0, stream>>>(eidx, E, ew, dinv, flags, nrm);
    k_mm1      <<<gMM1, b, 0, stream>>>(x, W1, flags, dinv, 0, bufA, N, 0);
    k_selfloop <<<gN32, b, 0, stream>>>(bufA, dinv, bufB, N);
    k_scatter  <<<gE32, b, 0, stream>>>(eidx, E, nrm, flags, bufA, bufB);
    k_mmh      <<<gMM,  b, 0, stream>>>(bufB, b1, 1, W2, flags, dinv, 0, bufA, N);
    k_selfloop <<<gN32, b, 0, stream>>>(bufA, dinv, bufB, N);
    k_scatter  <<<gE32, b, 0, stream>>>(eidx, E, nrm, flags, bufA, bufB);
    k_mmh      <<<gMM,  b, 0, stream>>>(bufB, b2, 1, W3, flags, dinv, 0, bufA, N);
    k_selfloop <<<gN32, b, 0, stream>>>(bufA, dinv, bufB, N);
    k_scatter  <<<gE32, b, 0, stream>>>(eidx, E, nrm, flags, bufA, bufB);
    k_pool<<<64, b, 0, stream>>>(bufB, b3, batch, flags, gpool, N);
    k_mlp <<<1,  b, 0, stream>>>(gpool, L1w, L1b, L2w, L2b, L3w, L3b, L4w, L4b, flags, d_out);
  }
}